// Round 1
// baseline (2793.841 us; speedup 1.0000x reference)
//
#include <hip/hip_runtime.h>

// CharLSTM on MI355X — layer-pipelined persistent LSTM.
// Structure: prep kernels -> persistent pipeline kernel (256 WGs: 8 layers x
// 2 batch-halves x 16 hidden-slices, flag-synchronized producer/consumer) -> FC.

typedef _Float16 f16;
typedef f16  f16x8 __attribute__((ext_vector_type(8)));
typedef f16  f16x4 __attribute__((ext_vector_type(4)));
typedef float f32x4 __attribute__((ext_vector_type(4)));
typedef int   i32x4 __attribute__((ext_vector_type(4)));

#define DEV __device__ __forceinline__

constexpr int TT = 512, BB = 64, VV = 100, HH = 256, LL = 8;
constexpr int RING_D = 64;

// ---- workspace layout (bytes) ----
constexpr size_t XE_OFF = 0;
constexpr size_t XE_SZ  = (size_t)TT*BB*256*2;        // embedded x, padded to 256, f16 [T][B][256]
constexpr size_t WP_OFF = XE_OFF + XE_SZ;
constexpr size_t WP_SZ  = (size_t)LL*16*64*512*2;     // repacked weights [L*16][64 gate-rows][512 k] f16
constexpr size_t BI_OFF = WP_OFF + WP_SZ;
constexpr size_t BI_SZ  = (size_t)LL*16*64*4;         // bias (b_ih+b_hh) [L*16][64] f32
constexpr size_t FW_OFF = BI_OFF + BI_SZ;
constexpr size_t FW_SZ  = (size_t)112*256*2;          // fc_w padded [112][256] f16
constexpr size_t H7_OFF = FW_OFF + FW_SZ;
constexpr size_t H7_SZ  = (size_t)TT*BB*256*2;        // layer-7 h history [T][B][256] f16
constexpr size_t RG_OFF = H7_OFF + H7_SZ;
constexpr size_t RG_SZ  = (size_t)7*RING_D*BB*256*2;  // rings for layers 0..6
constexpr size_t FP_OFF = RG_OFF + RG_SZ;
constexpr size_t FP_SZ  = (size_t)LL*TT*2*16;         // produced flags [L][T][hb][slice] bytes
constexpr size_t FCF_OFF = FP_OFF + FP_SZ;
constexpr size_t FCF_SZ  = (size_t)7*TT*2*16;         // consumed flags
// total ~56.96 MB

// ---- device-coherent helpers (cross-XCD: bypass L1/L2, go to coherent point) ----
DEV void glc_load_issue(i32x4& d, const void* p) {
  asm volatile("global_load_dwordx4 %0, %1, off sc0 sc1" : "=v"(d) : "v"(p));
}
DEV void glc_wait0() {
  asm volatile("s_waitcnt vmcnt(0)" ::: "memory");
  __builtin_amdgcn_sched_barrier(0);
}
DEV void glc_store16(void* p, i32x4 d) {
  asm volatile("global_store_dwordx4 %0, %1, off sc0 sc1" :: "v"(p), "v"(d) : "memory");
}
DEV void flag_store(unsigned char* p) {
  int one = 1;
  asm volatile("global_store_byte %0, %1, off sc0 sc1" :: "v"(p), "v"(one) : "memory");
}
// poll 16 one-byte flags; true = ready, false = timeout (avoids hard hang on logic bug)
DEV bool poll16(const unsigned char* p) {
  for (int it = 0; it < (1 << 22); ++it) {
    i32x4 f;
    asm volatile("global_load_dwordx4 %0, %1, off sc0 sc1\n\ts_waitcnt vmcnt(0)"
                 : "=v"(f) : "v"(p) : "memory");
    if ((f[0] & f[1] & f[2] & f[3]) == 0x01010101) return true;
    __builtin_amdgcn_s_sleep(2);
  }
  return false;
}

DEV float sigf(float x)   { return __builtin_amdgcn_rcpf(1.f + __expf(-x)); }
DEV float tanhf2(float x) { return 1.f - 2.f * __builtin_amdgcn_rcpf(1.f + __expf(2.f * x)); }
DEV unsigned short f16bits(float v) { f16 h = (f16)v; return __builtin_bit_cast(unsigned short, h); }

// =================== prep kernels ===================
__global__ void prep_zero(unsigned int* p) {         // grid 240x256 == 61440 dwords exactly
  p[blockIdx.x * 256 + threadIdx.x] = 0;
}

__global__ void prep_embed(const int* __restrict__ x, const float* __restrict__ em,
                           f16* __restrict__ xe) {   // grid 1024x256
  int g = blockIdx.x * 256 + threadIdx.x;            // (t,b) pair x 32-col chunk
  int chunk = g & 7, pair = g >> 3;
  int b = pair & 63, t = pair >> 6;
  int idx = x[b * 512 + t];
  const float* er = em + (size_t)idx * 100;
  f16* o = xe + (size_t)pair * 256 + chunk * 32;
  #pragma unroll
  for (int c4 = 0; c4 < 32; c4 += 4) {
    f16x4 v;
    #pragma unroll
    for (int q = 0; q < 4; ++q) {
      int c = chunk * 32 + c4 + q;
      v[q] = (c < 100) ? (f16)er[c] : (f16)0.f;
    }
    *(f16x4*)(o + c4) = v;
  }
}

// W row order: n = 4*unit_local + gate; r = 256*gate + 16*slice + unit_local
// k<256: input part (layer0: w_ih0 padded 100->256); k>=256: w_hh
__global__ void prep_w(const float* __restrict__ w_ih0, const float* __restrict__ w_ih,
                       const float* __restrict__ w_hh, f16* __restrict__ wpo) { // grid 4096x256
  int g = blockIdx.x * 256 + threadIdx.x;
  int k4 = (g & 127) * 4;
  int n  = (g >> 7) & 63;
  int ls = g >> 13;
  int l = ls >> 4, si = ls & 15;
  int r = 256 * (n & 3) + 16 * si + (n >> 2);
  f16x4 v;
  #pragma unroll
  for (int q = 0; q < 4; ++q) {
    int k = k4 + q;
    float f;
    if (k < 256) {
      if (l == 0) f = (k < 100) ? w_ih0[(size_t)r * 100 + k] : 0.f;
      else        f = w_ih[((size_t)(l - 1) * 1024 + r) * 256 + k];
    } else        f = w_hh[((size_t)l * 1024 + r) * 256 + (k - 256)];
    v[q] = (f16)f;
  }
  *(f16x4*)(wpo + (size_t)g * 4) = v;
}

__global__ void prep_bias(const float* __restrict__ b_ih, const float* __restrict__ b_hh,
                          float* __restrict__ bo) {  // grid 32x256
  int g = blockIdx.x * 256 + threadIdx.x;
  int n = g & 63, si = (g >> 6) & 15, l = g >> 10;
  int r = 256 * (n & 3) + 16 * si + (n >> 2);
  bo[g] = b_ih[l * 1024 + r] + b_hh[l * 1024 + r];
}

__global__ void prep_fcw(const float* __restrict__ fc_w, f16* __restrict__ fo) { // grid 28x256
  int g = blockIdx.x * 256 + threadIdx.x;
  int n = g >> 6, k4 = (g & 63) * 4;
  f16x4 v;
  #pragma unroll
  for (int q = 0; q < 4; ++q)
    v[q] = (n < 100) ? (f16)fc_w[(size_t)n * 256 + k4 + q] : (f16)0.f;
  *(f16x4*)(fo + (size_t)g * 4) = v;
}

// =================== persistent pipeline kernel ===================
// WG(layer, hb, slice): computes gates[32 batch rows][64 gate cols] each step.
// waves: wv = (mt | kh<<1): mt = M-tile (16 rows), kh = K-half (256 of 512).
// W half-K fragments persistent in VGPRs (4 N-tiles x 8 k-tiles = 128 VGPR).
__global__ void __launch_bounds__(256, 1) lstm_pipe(
    const f16* __restrict__ xe, const f16* __restrict__ wp, const float* __restrict__ biasp,
    f16* h7, f16* rings, unsigned char* fpf, unsigned char* fcf, float* out)
{
  __shared__ float lds_part[2][32][68];      // K-half partial sums (padded stride)
  __shared__ unsigned short lds_pub[32][16]; // h slice to publish (f16 bits)

  const int bx  = blockIdx.x;
  const int lyr = bx & 7;                    // one layer per XCD (round-robin heuristic)
  const int sub = bx >> 3;
  const int hb  = sub & 1;                   // batch half
  const int sl  = sub >> 1;                  // hidden slice (16 units)
  const int tid = threadIdx.x;
  const int wv  = tid >> 6;
  const int ln  = tid & 63;
  const int mt  = wv & 1;
  const int kh  = wv >> 1;

  // ---- persistent W fragments ----
  f16x8 wf0[8], wf1[8], wf2[8], wf3[8];
  {
    const f16* wb = wp + ((size_t)(lyr * 16 + sl)) * 64 * 512;
    int n15 = ln & 15, kof = (ln >> 4) * 8;
    #pragma unroll
    for (int kt = 0; kt < 8; ++kt) {
      int k = (kh * 8 + kt) * 32 + kof;
      wf0[kt] = *(const f16x8*)(wb + (size_t)(n15)*512 + k);
      wf1[kt] = *(const f16x8*)(wb + (size_t)(16 + n15) * 512 + k);
      wf2[kt] = *(const f16x8*)(wb + (size_t)(32 + n15) * 512 + k);
      wf3[kt] = *(const f16x8*)(wb + (size_t)(48 + n15) * 512 + k);
    }
  }
  float bias8[8];
  {
    const float* bb = biasp + (size_t)(lyr * 16 + sl) * 64 + (ln & 7) * 8;
    #pragma unroll
    for (int j = 0; j < 8; ++j) bias8[j] = bb[j];
  }
  const int grow = wv * 8 + (ln >> 3);   // gate-phase row (0..31)
  const int gc0  = (ln & 7) * 8;         // gate-phase col base: 2 units x 4 gates
  float c0 = 0.f, c1 = 0.f;              // fp32 cell state, lane-resident

  const f16* xsb = (lyr == 0) ? xe : rings + (size_t)(lyr - 1) * RING_D * 16384;
  const f16* hsb = (lyr == 7) ? h7 : rings + (size_t)lyr * RING_D * 16384;
  f16*       dsb = (lyr == 7) ? h7 : rings + (size_t)lyr * RING_D * 16384;

  const int arow = 32 * hb + mt * 16 + (ln & 15);
  const int akof = (ln >> 4) * 8;

  bool dead = false;   // poll timeout escape: degrade to wrong answer, never hang

  for (int t = 0; t < TT; ++t) {
    // ---- per-wave minimal polls ----
    if (kh == 0) {
      if (lyr > 0 && !dead)
        dead = !poll16(fpf + ((size_t)((lyr - 1) * TT + t) * 2 + hb) * 16);
    } else {
      if (t > 0 && !dead)
        dead = !poll16(fpf + ((size_t)(lyr * TT + (t - 1)) * 2 + hb) * 16);
    }

    // ---- A fragments straight from global (device-coherent) ----
    i32x4 af[8];
    if (kh == 1 && t == 0) {
      #pragma unroll
      for (int kt = 0; kt < 8; ++kt) af[kt] = i32x4{0, 0, 0, 0};
    } else {
      const f16* src;
      if (kh == 0) src = xsb + (size_t)(lyr == 0 ? t : (t & (RING_D - 1))) * 16384;
      else         src = hsb + (size_t)(lyr == 7 ? (t - 1) : ((t - 1) & (RING_D - 1))) * 16384;
      const f16* lp = src + (size_t)arow * 256 + akof;
      #pragma unroll
      for (int kt = 0; kt < 8; ++kt) glc_load_issue(af[kt], lp + kt * 32);
      glc_wait0();
    }

    // ---- MFMA: [32x256-half] x [256-half x 64] ----
    f32x4 a0 = {0,0,0,0}, a1 = {0,0,0,0}, a2 = {0,0,0,0}, a3 = {0,0,0,0};
    #pragma unroll
    for (int kt = 0; kt < 8; ++kt) {
      f16x8 av = __builtin_bit_cast(f16x8, af[kt]);
      a0 = __builtin_amdgcn_mfma_f32_16x16x32_f16(av, wf0[kt], a0, 0, 0, 0);
      a1 = __builtin_amdgcn_mfma_f32_16x16x32_f16(av, wf1[kt], a1, 0, 0, 0);
      a2 = __builtin_amdgcn_mfma_f32_16x16x32_f16(av, wf2[kt], a2, 0, 0, 0);
      a3 = __builtin_amdgcn_mfma_f32_16x16x32_f16(av, wf3[kt], a3, 0, 0, 0);
    }
    {
      int pr = mt * 16 + (ln >> 4) * 4;
      int pc = ln & 15;
      #pragma unroll
      for (int j = 0; j < 4; ++j) {
        lds_part[kh][pr + j][pc]      = a0[j];
        lds_part[kh][pr + j][16 + pc] = a1[j];
        lds_part[kh][pr + j][32 + pc] = a2[j];
        lds_part[kh][pr + j][48 + pc] = a3[j];
      }
    }
    __syncthreads();
    if (lyr > 0 && tid == 0)   // x-slot for step t fully consumed by this WG
      flag_store(fcf + ((size_t)((lyr - 1) * TT + t) * 2 + hb) * 16 + sl);

    // ---- gate phase: lane owns (row, 2 hidden units) ----
    float hot0, hot1;
    {
      const float* p0 = &lds_part[0][grow][gc0];
      const float* p1 = &lds_part[1][grow][gc0];
      float g[8];
      #pragma unroll
      for (int j = 0; j < 8; ++j) g[j] = p0[j] + p1[j] + bias8[j];
      float i0 = sigf(g[0]), ff0 = sigf(g[1]), z0 = tanhf2(g[2]), o0 = sigf(g[3]);
      c0 = ff0 * c0 + i0 * z0;  hot0 = o0 * tanhf2(c0);
      float i1 = sigf(g[4]), ff1 = sigf(g[5]), z1 = tanhf2(g[6]), o1 = sigf(g[7]);
      c1 = ff1 * c1 + i1 * z1;  hot1 = o1 * tanhf2(c1);
      unsigned int pk = ((unsigned int)f16bits(hot1) << 16) | f16bits(hot0);
      *(unsigned int*)&lds_pub[grow][(ln & 7) * 2] = pk;
      if (t == TT - 1) {   // final h/c outputs (fp32)
        size_t ob = 3276800 + (size_t)lyr * 16384 + (size_t)(32 * hb + grow) * 256
                  + sl * 16 + (ln & 7) * 2;
        out[ob]     = hot0;  out[ob + 1]     = hot1;
        out[ob + 131072] = c0;  out[ob + 131072 + 1] = c1;
      }
    }
    __syncthreads();

    // ---- publish h slice (wave 0 only) ----
    if (wv == 0) {
      if (lyr < 7 && t >= RING_D && !dead)  // backpressure: slot t-64 consumed?
        dead = !poll16(fcf + ((size_t)(lyr * TT + (t - RING_D)) * 2 + hb) * 16);
      f16* dst = dsb + (size_t)(lyr == 7 ? t : (t & (RING_D - 1))) * 16384
               + (size_t)(32 * hb + (ln >> 1)) * 256 + sl * 16 + (ln & 1) * 8;
      i32x4 pd = ((const i32x4*)&lds_pub[0][0])[ln];
      glc_store16(dst, pd);
      asm volatile("s_waitcnt vmcnt(0)" ::: "memory");
      if (ln == 0)
        flag_store(fpf + ((size_t)(lyr * TT + t) * 2 + hb) * 16 + sl);
    }
  }
}

// =================== final FC ===================
__global__ void __launch_bounds__(256, 1) fc_kernel(
    const f16* __restrict__ h7, const f16* __restrict__ fcw,
    const float* __restrict__ fcb, float* __restrict__ out)
{
  const int t  = blockIdx.x;
  const int wv = threadIdx.x >> 6;   // M-tile (16 batch rows)
  const int ln = threadIdx.x & 63;
  const f16* ab = h7 + (size_t)t * 16384 + (size_t)(wv * 16 + (ln & 15)) * 256 + (ln >> 4) * 8;
  f16x8 af[8];
  #pragma unroll
  for (int kt = 0; kt < 8; ++kt) af[kt] = *(const f16x8*)(ab + kt * 32);
  const int obrow = wv * 16 + (ln >> 4) * 4;
  #pragma unroll
  for (int nt = 0; nt < 7; ++nt) {
    const f16* bb = fcw + (size_t)(nt * 16 + (ln & 15)) * 256 + (ln >> 4) * 8;
    f32x4 acc = {0, 0, 0, 0};
    #pragma unroll
    for (int kt = 0; kt < 8; ++kt) {
      f16x8 bv = *(const f16x8*)(bb + kt * 32);
      acc = __builtin_amdgcn_mfma_f32_16x16x32_f16(af[kt], bv, acc, 0, 0, 0);
    }
    int vg = nt * 16 + (ln & 15);
    if (vg < VV) {
      float bias = fcb[vg];
      #pragma unroll
      for (int j = 0; j < 4; ++j)
        out[(size_t)(obrow + j) * 51200 + (size_t)t * 100 + vg] = acc[j] + bias;
    }
  }
}

// =================== launch ===================
extern "C" void kernel_launch(void* const* d_in, const int* in_sizes, int n_in,
                              void* d_out, int out_size, void* d_ws, size_t ws_size,
                              hipStream_t stream) {
  (void)in_sizes; (void)n_in; (void)out_size; (void)ws_size;
  const int*   x     = (const int*)d_in[0];
  const float* embed = (const float*)d_in[1];
  const float* w_ih0 = (const float*)d_in[2];
  const float* w_ih  = (const float*)d_in[3];
  const float* w_hh  = (const float*)d_in[4];
  const float* b_ih  = (const float*)d_in[5];
  const float* b_hh  = (const float*)d_in[6];
  const float* fc_w  = (const float*)d_in[7];
  const float* fc_b  = (const float*)d_in[8];
  char* ws = (char*)d_ws;
  float* out = (float*)d_out;

  // flags must be re-zeroed every call (ws is poisoned once, not restored)
  prep_zero<<<240, 256, 0, stream>>>((unsigned int*)(ws + FP_OFF));
  prep_embed<<<1024, 256, 0, stream>>>(x, embed, (f16*)(ws + XE_OFF));
  prep_w<<<4096, 256, 0, stream>>>(w_ih0, w_ih, w_hh, (f16*)(ws + WP_OFF));
  prep_bias<<<32, 256, 0, stream>>>(b_ih, b_hh, (float*)(ws + BI_OFF));
  prep_fcw<<<28, 256, 0, stream>>>(fc_w, (f16*)(ws + FW_OFF));

  // dynamic LDS pad: static 18432 + 63744 = 82176 B > 80 KiB -> forces 1 WG/CU
  lstm_pipe<<<256, 256, 63744, stream>>>(
      (const f16*)(ws + XE_OFF), (const f16*)(ws + WP_OFF), (const float*)(ws + BI_OFF),
      (f16*)(ws + H7_OFF), (f16*)(ws + RG_OFF),
      (unsigned char*)(ws + FP_OFF), (unsigned char*)(ws + FCF_OFF), out);

  fc_kernel<<<512, 256, 0, stream>>>((const f16*)(ws + H7_OFF), (const f16*)(ws + FW_OFF),
                                     fc_b, out);
}